// Round 9
// baseline (70.682 us; speedup 1.0000x reference)
//
#include <hip/hip_runtime.h>
#include <hip/hip_bf16.h>

#define N_NODES 4096
#define F_IN    128
#define HEADS   4
#define FTOT    128
#define NSPLIT  4
#define NRANGE  (N_NODES / NSPLIT)   // 1024
#define NSTEP   (NRANGE / 64)        // 16
#define HPB     512                  // k_pre hp blocks (8 nodes each)
#define BITB    1024                 // k_pre bit-transpose blocks (64 cols x 256 rows)
#define L2E     1.4426950408889634f

typedef __attribute__((ext_vector_type(8)))  short  short8v;
typedef __attribute__((ext_vector_type(16))) float  float16v;

static __device__ __forceinline__ unsigned f2bfu(float f) {
    union { __hip_bfloat16 h; unsigned short u; } cv;
    cv.h = __float2bfloat16(f);
    return (unsigned)cv.u;
}

// ---------------- kernel 1: heterogeneous pre-pass ----------------
// blocks [0,HPB): h_prime -> bf16 TRANSPOSED hpt[f][n]; alpha_src/dst -> transposed,
//                 log2e-prescaled ast/adt[h][n].
// blocks [HPB,HPB+BITB): adj (67 MB) -> bit-transposed mask abits[m][n-bits] (2 MB).
__global__ __launch_bounds__(256)
void k_pre(const float* __restrict__ x, const float* __restrict__ W,
           const float* __restrict__ att_src, const float* __restrict__ att_dst,
           const float* __restrict__ adj,
           unsigned short* __restrict__ hpt, float* __restrict__ ast,
           float* __restrict__ adt, unsigned* __restrict__ abits)
{
    const int t = threadIdx.x;
    if (blockIdx.x < HPB) {
        // ---------- hp path: 8 nodes, 2 sub-groups of 128 threads ----------
        __shared__ alignas(16) float    xs[8 * F_IN];
        __shared__ alignas(16) unsigned hs[F_IN * 4];    // [f][4 u32] = 8 bf16 nodes per f
        __shared__ float ssa[4][8], ssd[4][8];
        const int sub = t >> 7;
        const int tt  = t & 127;             // out-feature
        const int i0  = blockIdx.x * 8;
        reinterpret_cast<float4*>(xs)[t] =
            reinterpret_cast<const float4*>(x + (size_t)i0 * F_IN)[t];
        __syncthreads();

        const float4* W4  = reinterpret_cast<const float4*>(W + tt * F_IN);
        const float4* xs4 = reinterpret_cast<const float4*>(xs + sub * 4 * F_IN);
        float a0 = 0.f, a1 = 0.f, a2 = 0.f, a3 = 0.f;
#pragma unroll
        for (int k = 0; k < F_IN / 4; ++k) {
            const float4 w  = W4[k];
            const float4 v0 = xs4[k], v1 = xs4[32 + k], v2 = xs4[64 + k], v3 = xs4[96 + k];
            a0 = fmaf(w.x, v0.x, a0); a0 = fmaf(w.y, v0.y, a0); a0 = fmaf(w.z, v0.z, a0); a0 = fmaf(w.w, v0.w, a0);
            a1 = fmaf(w.x, v1.x, a1); a1 = fmaf(w.y, v1.y, a1); a1 = fmaf(w.z, v1.z, a1); a1 = fmaf(w.w, v1.w, a1);
            a2 = fmaf(w.x, v2.x, a2); a2 = fmaf(w.y, v2.y, a2); a2 = fmaf(w.z, v2.z, a2); a2 = fmaf(w.w, v2.w, a2);
            a3 = fmaf(w.x, v3.x, a3); a3 = fmaf(w.y, v3.y, a3); a3 = fmaf(w.z, v3.z, a3); a3 = fmaf(w.w, v3.w, a3);
        }
        // pack 4 bf16 into 2 u32 words of this f-row (nodes sub*4..+3)
        hs[tt * 4 + sub * 2 + 0] = f2bfu(a0) | (f2bfu(a1) << 16);
        hs[tt * 4 + sub * 2 + 1] = f2bfu(a2) | (f2bfu(a3) << 16);

        const float asv = att_src[tt], adv = att_dst[tt];
        float s0 = a0 * asv, s1 = a1 * asv, s2 = a2 * asv, s3 = a3 * asv;
        float d0 = a0 * adv, d1 = a1 * adv, d2 = a2 * adv, d3 = a3 * adv;
#pragma unroll
        for (int s = 16; s; s >>= 1) {
            s0 += __shfl_xor(s0, s); s1 += __shfl_xor(s1, s);
            s2 += __shfl_xor(s2, s); s3 += __shfl_xor(s3, s);
            d0 += __shfl_xor(d0, s); d1 += __shfl_xor(d1, s);
            d2 += __shfl_xor(d2, s); d3 += __shfl_xor(d3, s);
        }
        if ((tt & 31) == 0) {
            const int hh = tt >> 5;
            ssa[hh][sub * 4 + 0] = s0 * L2E; ssa[hh][sub * 4 + 1] = s1 * L2E;
            ssa[hh][sub * 4 + 2] = s2 * L2E; ssa[hh][sub * 4 + 3] = s3 * L2E;
            ssd[hh][sub * 4 + 0] = d0 * L2E; ssd[hh][sub * 4 + 1] = d1 * L2E;
            ssd[hh][sub * 4 + 2] = d2 * L2E; ssd[hh][sub * 4 + 3] = d3 * L2E;
        }
        __syncthreads();
        if (t < 128)   // flush one 16B row-segment of hpt per f
            *reinterpret_cast<uint4*>(hpt + (size_t)t * N_NODES + i0) =
                *reinterpret_cast<const uint4*>(&hs[t * 4]);
        if (t < 64) {  // flush alphas: [sd][h][node]
            const int sd = t >> 5, hh = (t >> 3) & 3, nn = t & 7;
            const float v = sd ? ssd[hh][nn] : ssa[hh][nn];
            (sd ? adt : ast)[hh * N_NODES + i0 + nn] = v;
        }
    } else {
        // ---------- bits path: strip of 64 m-cols x chunk of 256 n-rows ----------
        __shared__ alignas(16) unsigned short lb[64 * 16];   // [m][16 u16] = 256 n-bits per m
        const int sblk  = blockIdx.x - HPB;
        const int strip = sblk & 63;
        const int chunk = sblk >> 6;             // 0..15
        const int c0    = strip * 64;
        const int r0    = chunk * 256;
        const int q     = t & 15;                // m-quad
        const int p     = t >> 4;                // 16-consecutive-n group
        const float4* adj4 = reinterpret_cast<const float4*>(adj);

        float4 v[16];
#pragma unroll
        for (int it = 0; it < 16; ++it)
            v[it] = adj4[(size_t)(r0 + p * 16 + it) * (N_NODES / 4) + (c0 >> 2) + q];
        unsigned mk0 = 0, mk1 = 0, mk2 = 0, mk3 = 0;
#pragma unroll
        for (int it = 0; it < 16; ++it) {
            mk0 |= (v[it].x != 0.f) ? (1u << it) : 0u;
            mk1 |= (v[it].y != 0.f) ? (1u << it) : 0u;
            mk2 |= (v[it].z != 0.f) ? (1u << it) : 0u;
            mk3 |= (v[it].w != 0.f) ? (1u << it) : 0u;
        }
        lb[(4 * q + 0) * 16 + p] = (unsigned short)mk0;
        lb[(4 * q + 1) * 16 + p] = (unsigned short)mk1;
        lb[(4 * q + 2) * 16 + p] = (unsigned short)mk2;
        lb[(4 * q + 3) * 16 + p] = (unsigned short)mk3;
        __syncthreads();
        const unsigned* lb32 = reinterpret_cast<const unsigned*>(lb);
#pragma unroll
        for (int j = 0; j < 2; ++j) {
            const int w = t + j * 256;           // 512 u32 total
            const int m = w >> 3, col = w & 7;
            abits[(size_t)(c0 + m) * (N_NODES / 32) + chunk * 8 + col] = lb32[w];
        }
    }
}

// ---------------- kernel 2: dense fused MFMA aggregation ----------------
// Block: 32 m-rows, 4 waves (wave = head), n-range = NRANGE per split.
// Per K16: lane builds A-frag w[m=l&31][k=(l>>5)*8+i] in regs (bits+exp2),
// B-frag = ds_read_b128 from XOR-swizzled hpt tile; mfma 32x32x16 bf16.
__global__ __launch_bounds__(256)
void k_main(const unsigned short* __restrict__ hpt, const float* __restrict__ ast,
            const float* __restrict__ adt, const unsigned* __restrict__ abits,
            float* __restrict__ z_part, float* __restrict__ taup)
{
    __shared__ alignas(16) unsigned short hps[128 * 64];   // [f][64 n] bf16, swizzled, 16 KB
    __shared__ alignas(16) unsigned       bts[32 * 32];    // [m][128 B n-bits], swizzled, 4 KB
    char* hps_c = reinterpret_cast<char*>(hps);
    char* bts_c = reinterpret_cast<char*>(bts);

    const int t     = threadIdx.x;
    const int wv    = t >> 6;                  // head
    const int l     = t & 63;
    const int np    = l >> 5;
    const int lm    = l & 31;
    const int mt    = blockIdx.x >> 2;
    const int split = blockIdx.x & 3;
    const int m0    = mt * 32;
    const int nb0   = split * NRANGE;

    // stage bits tile [32][128B] (reg-staged, swizzled)
    {
        const int m = t >> 3, part = t & 7;
        uint4 v = *reinterpret_cast<const uint4*>(
            abits + (size_t)(m0 + m) * (N_NODES / 32) + split * 32 + part * 4);
        const unsigned byte = (unsigned)(t * 16) ^ ((m & 7) << 4);
        *reinterpret_cast<uint4*>(bts_c + byte) = v;
    }
    auto stage_hp = [&](int step) {
        const int nb = nb0 + step * 64;
#pragma unroll
        for (int j = 0; j < 4; ++j) {          // 1024 uint4 = full 128-row tile
            const int lin = t + j * 256;
            const int f = lin >> 3, part = lin & 7;
            uint4 v = *reinterpret_cast<const uint4*>(
                hpt + (size_t)f * N_NODES + nb + part * 8);
            const unsigned byte = (unsigned)(lin * 16) ^ ((f & 7) << 4);
            *reinterpret_cast<uint4*>(hps_c + byte) = v;
        }
    };

    const float adm = adt[wv * N_NODES + m0 + lm];
    const float* asw = ast + wv * N_NODES + nb0;

    float16v acc;
#pragma unroll
    for (int r = 0; r < 16; ++r) acc[r] = 0.f;
    float tau = 0.f;

    stage_hp(0);
    __syncthreads();
    for (int step = 0;;) {
        // bits for this K64: one b64 per lane
        const unsigned baddr = (unsigned)(lm * 128 + step * 8) ^ ((lm & 7) << 4);
        const unsigned long long b64 =
            *reinterpret_cast<const unsigned long long*>(bts_c + baddr);
        const int nb = step * 64;
#pragma unroll
        for (int q = 0; q < 4; ++q) {
            const float* ap = asw + nb + q * 16 + np * 8;
            const float4 a0 = *reinterpret_cast<const float4*>(ap);
            const float4 a1 = *reinterpret_cast<const float4*>(ap + 4);
            const unsigned bb = (unsigned)(b64 >> ((2 * q + np) * 8)) & 0xFFu;
            auto wq = [&](float a, unsigned bit) {
                const float c  = a + adm;
                const float ex = exp2f(fmaxf(0.2f * c, c));
                const float w  = (bb & bit) ? ex : 0.f;
                tau += w;
                return w;
            };
            const float w0 = wq(a0.x, 1u),  w1 = wq(a0.y, 2u);
            const float w2 = wq(a0.z, 4u),  w3 = wq(a0.w, 8u);
            const float w4 = wq(a1.x, 16u), w5 = wq(a1.y, 32u);
            const float w6 = wq(a1.z, 64u), w7 = wq(a1.w, 128u);
            union { short8v v; unsigned u[4]; } af;
            af.u[0] = f2bfu(w0) | (f2bfu(w1) << 16);
            af.u[1] = f2bfu(w2) | (f2bfu(w3) << 16);
            af.u[2] = f2bfu(w4) | (f2bfu(w5) << 16);
            af.u[3] = f2bfu(w6) | (f2bfu(w7) << 16);
            const unsigned bofs =
                (unsigned)((wv * 32 + lm) * 128 + (q * 16 + np * 8) * 2) ^ ((lm & 7) << 4);
            const short8v bv = *reinterpret_cast<const short8v*>(hps_c + bofs);
            acc = __builtin_amdgcn_mfma_f32_32x32x16_bf16(af.v, bv, acc, 0, 0, 0);
        }
        if (++step == NSTEP) break;
        __syncthreads();
        stage_hp(step);
        __syncthreads();
    }

    // tau: combine np halves; write [split][h][m]
    tau += __shfl_xor(tau, 32);
    if (np == 0)
        taup[((size_t)split * HEADS + wv) * N_NODES + m0 + lm] = tau;
    // z: C/D layout col=lane&31, row=(r&3)+8*(r>>2)+4*np  [m74/m101]
    float* zp = z_part + (size_t)split * N_NODES * FTOT;
#pragma unroll
    for (int r = 0; r < 16; ++r) {
        const int row = (r & 3) + 8 * (r >> 2) + 4 * np;
        zp[(size_t)(m0 + row) * FTOT + wv * 32 + lm] = acc[r];
    }
}

// ---------------- kernel 3: merge splits, divide by tau, add bias ----------------
__global__ __launch_bounds__(256)
void k_fin(const float* __restrict__ z_part, const float* __restrict__ taup,
           const float* __restrict__ bias, float* __restrict__ out)
{
    const int idx = blockIdx.x * 256 + threadIdx.x;  // over N*FTOT/4 float4s
    const int m = idx >> 5, f4 = idx & 31, h = f4 >> 3;
    const float4* zp4 = reinterpret_cast<const float4*>(z_part);
    float4 z = make_float4(0.f, 0.f, 0.f, 0.f);
    float ts = 0.f;
#pragma unroll
    for (int s = 0; s < NSPLIT; ++s) {
        const float4 zs = zp4[(size_t)s * N_NODES * (FTOT / 4) + idx];
        z.x += zs.x; z.y += zs.y; z.z += zs.z; z.w += zs.w;
        ts += taup[((size_t)s * HEADS + h) * N_NODES + m];
    }
    const float inv = 1.f / ts;
    const float4 b = reinterpret_cast<const float4*>(bias)[f4];
    float4 o;
    o.x = z.x * inv + b.x; o.y = z.y * inv + b.y;
    o.z = z.z * inv + b.z; o.w = z.w * inv + b.w;
    reinterpret_cast<float4*>(out)[idx] = o;
}

extern "C" void kernel_launch(void* const* d_in, const int* in_sizes, int n_in,
                              void* d_out, int out_size, void* d_ws, size_t ws_size,
                              hipStream_t stream) {
    const float* x       = (const float*)d_in[0];
    const float* adj     = (const float*)d_in[1];
    const float* weight  = (const float*)d_in[2];
    const float* att_src = (const float*)d_in[3];
    const float* att_dst = (const float*)d_in[4];
    const float* bias    = (const float*)d_in[5];
    float* out = (float*)d_out;

    // ws: hpt 1MB | ast 64KB | adt 64KB | abits 2MB | z_part 8MB | taup 256KB
    unsigned short* hpt = (unsigned short*)d_ws;
    float* ast = (float*)(hpt + (size_t)FTOT * N_NODES);
    float* adt = ast + (size_t)HEADS * N_NODES;
    unsigned* abits = (unsigned*)(adt + (size_t)HEADS * N_NODES);
    float* z_part = (float*)(abits + (size_t)N_NODES * (N_NODES / 32));
    float* taup = z_part + (size_t)NSPLIT * N_NODES * FTOT;

    k_pre <<<HPB + BITB, 256, 0, stream>>>(x, weight, att_src, att_dst, adj,
                                           hpt, ast, adt, abits);
    k_main<<<(N_NODES / 32) * NSPLIT, 256, 0, stream>>>(hpt, ast, adt, abits,
                                                        z_part, taup);
    k_fin <<<N_NODES * (FTOT / 4) / 256, 256, 0, stream>>>(z_part, taup, bias, out);
}